// Round 4
// baseline (172.382 us; speedup 1.0000x reference)
//
#include <hip/hip_runtime.h>
#include <hip/hip_bf16.h>

// Problem constants
#define NUM_NODES 500000
#define DD  128
#define UU  32
#define TT  4
#define AA  32
#define NSRC 65536
#define BB  8192
#define EE  262144                  // = 2^18
#define NEDGE (TT * EE)             // 2^20
#define NBKT (BB * TT)              // 32768 buckets, id = dst*4 + t
#define AGG_FLOATS (BB * TT * UU)   // 1,048,576 floats = 4 MB
#define NB  16                      // output nodes per block in node_kernel

// ---------------- zero int counters ----------------
__global__ __launch_bounds__(256) void zero_cnt_kernel(int4* __restrict__ p) {
    int i = blockIdx.x * 256 + threadIdx.x;   // covers NBKT/4 = 8192
    p[i] = make_int4(0, 0, 0, 0);
}

// ---------------- zero agg (fallback path) ----------------
__global__ __launch_bounds__(256) void zero_agg_kernel(float4* __restrict__ p) {
    int i = blockIdx.x * 256 + threadIdx.x;   // covers AGG_FLOATS/4
    p[i] = make_float4(0.f, 0.f, 0.f, 0.f);
}

// ---------------- histogram of (dst,t) ----------------
__global__ __launch_bounds__(256) void hist_kernel(
    const int* __restrict__ edge_dst, int* __restrict__ cnt)
{
    int i = blockIdx.x * 256 + threadIdx.x;   // edge id in [0, NEDGE)
    int t = i >> 18;                           // E = 2^18
    int dst = edge_dst[i];
    atomicAdd(&cnt[dst * 4 + t], 1);
}

// ---------------- single-block exclusive scan of 32768 counters ----------
__global__ __launch_bounds__(1024) void scan_kernel(
    const int* __restrict__ cnt, int* __restrict__ base, int* __restrict__ cursor)
{
    __shared__ int partial[1024];
    int tid = threadIdx.x;
    int4 v[8];
    const int4* c4 = (const int4*)cnt + tid * 8;
    int s = 0;
    #pragma unroll
    for (int i = 0; i < 8; ++i) {
        v[i] = c4[i];
        s += v[i].x + v[i].y + v[i].z + v[i].w;
    }
    partial[tid] = s;
    __syncthreads();
    // Hillis-Steele inclusive scan over 1024 partials
    for (int off = 1; off < 1024; off <<= 1) {
        int add = (tid >= off) ? partial[tid - off] : 0;
        __syncthreads();
        partial[tid] += add;
        __syncthreads();
    }
    int run = (tid > 0) ? partial[tid - 1] : 0;   // exclusive base for my chunk
    #pragma unroll
    for (int i = 0; i < 8; ++i) {
        int4 b;
        b.x = run; run += v[i].x;
        b.y = run; run += v[i].y;
        b.z = run; run += v[i].z;
        b.w = run; run += v[i].w;
        ((int4*)base)[tid * 8 + i]   = b;
        ((int4*)cursor)[tid * 8 + i] = b;
    }
}

// ---------------- scatter edges into buckets ----------------
__global__ __launch_bounds__(256) void scatter_kernel(
    const int* __restrict__ input_nodes,
    const int* __restrict__ edge_src,
    const int* __restrict__ edge_dst,
    int* __restrict__ cursor,
    int* __restrict__ sortedNode)
{
    int i = blockIdx.x * 256 + threadIdx.x;
    int t = i >> 18;
    int dst = edge_dst[i];
    int pos = atomicAdd(&cursor[dst * 4 + t], 1);
    sortedNode[pos] = input_nodes[edge_src[i]];
}

// ---------------- gather: one wave per bucket, no atomics ----------------
__global__ __launch_bounds__(256) void gather_kernel(
    const float* __restrict__ nte_in,      // [NUM_NODES][128]
    const int* __restrict__ sortedNode,
    const int* __restrict__ base,
    const int* __restrict__ cnt,
    float* __restrict__ agg)               // [B][T][U]
{
    int wv = threadIdx.x >> 6, lane = threadIdx.x & 63;
    int k = blockIdx.x * 4 + wv;           // bucket = dst*4 + t
    int t = k & 3, dst = k >> 2;
    int start = base[k], n = cnt[k];
    int e = lane >> 5, u = lane & 31;
    const float* src = nte_in + t * 32 + u;
    float acc0 = 0.f, acc1 = 0.f;
    int j = 0;
    for (; j + 4 <= n; j += 4) {
        int n0 = sortedNode[start + j + e];
        int n1 = sortedNode[start + j + 2 + e];
        acc0 += src[(long)n0 * 128];
        acc1 += src[(long)n1 * 128];
    }
    for (; j < n; j += 2) {
        if (j + e < n) {
            int n0 = sortedNode[start + j + e];
            acc0 += src[(long)n0 * 128];
        }
    }
    float acc = acc0 + acc1;
    acc += __shfl_xor(acc, 32, 64);
    if (lane < 32) agg[dst * 128 + t * 32 + u] = acc;
}

// ---------------- fallback: direct atomic scatter (proven, round 2) ------
__global__ __launch_bounds__(256) void edge_atomic_kernel(
    const float* __restrict__ nte_in,
    const int* __restrict__ input_nodes,
    const int* __restrict__ edge_src,
    const int* __restrict__ edge_dst,
    float* __restrict__ agg)
{
    int tid = blockIdx.x * 256 + threadIdx.x;
    int i = tid >> 5;
    int u = tid & 31;
    int t = i >> 18;
    int src = edge_src[i];
    int dst = edge_dst[i];
    int node = input_nodes[src];
    float v = nte_in[node * 128 + t * 32 + u];
    atomicAdd(&agg[dst * 128 + t * 32 + u], v);
}

// ---------------- per-output-node attention + transform ------------------
__global__ __launch_bounds__(256) void node_kernel(
    const float* __restrict__ node_emb,          // [NUM_NODES][D]
    const float* __restrict__ w,                 // [T][U][D]
    const float* __restrict__ s1,                // [T][U][A]
    const float* __restrict__ s2,                // [T][A]
    const int* __restrict__ output_nodes,        // [B]
    const float* __restrict__ agg,               // [B][T][U]
    float* __restrict__ out)                     // [B][T][D]
{
    __shared__ float s_nte[NB][TT * UU];   // 8 KB
    __shared__ float s_comb[NB][UU];       // 2 KB
    __shared__ float s_sc[NB][TT];
    __shared__ int   s_node[NB];

    int tid  = threadIdx.x;
    int wv   = tid >> 6;
    int lane = tid & 63;
    int b0   = blockIdx.x * NB;

    // stage agg rows for 16 b's: 2048 f32 = 512 float4
    {
        const float4* av = (const float4*)(agg + b0 * 128);
        float4* sv = (float4*)&s_nte[0][0];
        sv[tid]       = av[tid];
        sv[tid + 256] = av[tid + 256];
    }
    if (tid < NB) s_node[tid] = output_nodes[b0 + tid];
    __syncthreads();

    // ---- Phase A: attention scores ----
    int a  = lane & 31;
    int th = lane >> 5;              // 0 or 1
    int t0 = th, t1 = th + 2;
    float s1a[UU], s1b[UU];
    #pragma unroll
    for (int u = 0; u < UU; ++u) {
        s1a[u] = s1[(t0 * UU + u) * AA + a];
        s1b[u] = s1[(t1 * UU + u) * AA + a];
    }
    float s2a = s2[t0 * AA + a];
    float s2b = s2[t1 * AA + a];

    #pragma unroll
    for (int q = 0; q < 4; ++q) {
        int bl = wv * 4 + q;
        float acc0 = 0.f, acc1 = 0.f;
        #pragma unroll
        for (int u = 0; u < UU; ++u) {
            acc0 += s_nte[bl][t0 * UU + u] * s1a[u];
            acc1 += s_nte[bl][t1 * UU + u] * s1b[u];
        }
        float p0 = tanhf(acc0) * s2a;
        float p1 = tanhf(acc1) * s2b;
        #pragma unroll
        for (int m = 1; m < 32; m <<= 1) {
            p0 += __shfl_xor(p0, m, 64);
            p1 += __shfl_xor(p1, m, 64);
        }
        if ((lane & 31) == 0) { s_sc[bl][th] = p0; s_sc[bl][th + 2] = p1; }
    }
    __syncthreads();

    // softmax + combined for this wave's 4 b's
    #pragma unroll
    for (int q = 0; q < 4; ++q) {
        int bl = wv * 4 + q;
        float sc0 = s_sc[bl][0], sc1 = s_sc[bl][1];
        float sc2 = s_sc[bl][2], sc3 = s_sc[bl][3];
        float mx = fmaxf(fmaxf(sc0, sc1), fmaxf(sc2, sc3));
        float e0 = expf(sc0 - mx), e1 = expf(sc1 - mx);
        float e2 = expf(sc2 - mx), e3 = expf(sc3 - mx);
        float isum = 1.f / (e0 + e1 + e2 + e3);
        if (lane < 32) {
            float c = e0 * isum * s_nte[bl][a]
                    + e1 * isum * s_nte[bl][UU + a]
                    + e2 * isum * s_nte[bl][2 * UU + a]
                    + e3 * isum * s_nte[bl][3 * UU + a];
            s_comb[bl][a] = c;
        }
    }
    __syncthreads();

    // ---- Phase B: transform + add emb + normalize; wave == t ----
    int t = wv;
    const float* wt = w + t * (UU * DD);
    float wA[UU], wB[UU];
    #pragma unroll
    for (int u = 0; u < UU; ++u) {
        wA[u] = wt[u * DD + lane];
        wB[u] = wt[u * DD + lane + 64];
    }
    for (int bl = 0; bl < NB; ++bl) {
        int node = s_node[bl];
        float accA = node_emb[(long)node * DD + lane];
        float accB = node_emb[(long)node * DD + lane + 64];
        #pragma unroll
        for (int u = 0; u < UU; ++u) {
            float c = s_comb[bl][u];
            accA += c * wA[u];
            accB += c * wB[u];
        }
        float sq = accA * accA + accB * accB;
        #pragma unroll
        for (int m = 1; m < 64; m <<= 1)
            sq += __shfl_xor(sq, m, 64);
        float invn = 1.f / fmaxf(sqrtf(sq), 1e-12f);
        int ob = (b0 + bl) * (TT * DD) + t * DD;
        out[ob + lane]      = accA * invn;
        out[ob + lane + 64] = accB * invn;
    }
}

extern "C" void kernel_launch(void* const* d_in, const int* in_sizes, int n_in,
                              void* d_out, int out_size, void* d_ws, size_t ws_size,
                              hipStream_t stream) {
    const float* node_emb = (const float*)d_in[0];
    const float* nte_in   = (const float*)d_in[1];
    const float* w        = (const float*)d_in[2];
    const float* s1       = (const float*)d_in[3];
    const float* s2       = (const float*)d_in[4];
    const int* input_nodes  = (const int*)d_in[5];
    const int* output_nodes = (const int*)d_in[6];
    const int* edge_src     = (const int*)d_in[7];
    const int* edge_dst     = (const int*)d_in[8];
    float* out = (float*)d_out;

    // workspace layout
    char* ws = (char*)d_ws;
    float* agg       = (float*)ws;                        // 4 MB
    int*   cnt       = (int*)(ws + AGG_FLOATS * 4);       // 128 KB
    int*   base      = cnt + NBKT;                        // 128 KB
    int*   cursor    = base + NBKT;                       // 128 KB
    int*   sortedNode= cursor + NBKT;                     // 4 MB
    size_t need = (size_t)AGG_FLOATS * 4 + 3u * NBKT * 4 + (size_t)NEDGE * 4;

    if (ws_size >= need) {
        // sorted (atomic-free scatter) path
        zero_cnt_kernel<<<dim3(NBKT / 4 / 256), dim3(256), 0, stream>>>((int4*)cnt);
        hist_kernel<<<dim3(NEDGE / 256), dim3(256), 0, stream>>>(edge_dst, cnt);
        scan_kernel<<<dim3(1), dim3(1024), 0, stream>>>(cnt, base, cursor);
        scatter_kernel<<<dim3(NEDGE / 256), dim3(256), 0, stream>>>(
            input_nodes, edge_src, edge_dst, cursor, sortedNode);
        gather_kernel<<<dim3(NBKT / 4), dim3(256), 0, stream>>>(
            nte_in, sortedNode, base, cnt, agg);
    } else {
        // fallback: direct fp-atomic scatter
        zero_agg_kernel<<<dim3(AGG_FLOATS / 4 / 256), dim3(256), 0, stream>>>((float4*)agg);
        edge_atomic_kernel<<<dim3((NEDGE * 32) / 256), dim3(256), 0, stream>>>(
            nte_in, input_nodes, edge_src, edge_dst, agg);
    }

    node_kernel<<<dim3(BB / NB), dim3(256), 0, stream>>>(
        node_emb, w, s1, s2, output_nodes, agg, out);
}